// Round 3
// baseline (491.522 us; speedup 1.0000x reference)
//
#include <hip/hip_runtime.h>

// CrossTableAttention on MI355X (gfx950)
// T=16 B=1024 D=1024 R=8 H=16 DH=64
//
// R2: fix cvt_w4 grid/index bug (R1 converted only 1/4 of each weight matrix);
//     drop the provably-neutral LDS slot swizzle (back to R0-verified staging);
//     attn2 output now staged through LDS -> coalesced 128B stores.

typedef unsigned short u16;
typedef __attribute__((ext_vector_type(8))) short short8;   // 8 bf16 = 4 VGPRs
typedef __attribute__((ext_vector_type(4))) float f32x4;

__device__ __forceinline__ float bf2f(u16 u) {
  unsigned int x = ((unsigned int)u) << 16;
  return __uint_as_float(x);
}
__device__ __forceinline__ u16 f2bf(float f) {
  unsigned int x = __float_as_uint(f);
  unsigned int r = (x + 0x7fffu + ((x >> 16) & 1u)) >> 16;   // RNE
  return (u16)r;
}

// async global->LDS, 16B per lane; lds dest is wave-uniform base + lane*16
__device__ __forceinline__ void gld_lds16(const void* g, void* l) {
  __builtin_amdgcn_global_load_lds(
      (const __attribute__((address_space(1))) unsigned int*)(unsigned long long)g,
      (__attribute__((address_space(3))) unsigned int*)(unsigned int)(unsigned long long)l,
      16, 0, 0);
}

// ---------------------------------------------------------------- prep kernels

__global__ void relw_kernel(const float* __restrict__ rel_embs,
                            const float* __restrict__ w_rel,
                            const float* __restrict__ b_rel,
                            float* __restrict__ rel_w) {
  const int tr = blockIdx.x;            // t*8 + r, 128 total
  const float* row = rel_embs + (size_t)tr * 1024;
  const int lane = threadIdx.x;         // 64 threads
  float s = 0.f;
  for (int i = lane; i < 1024; i += 64) s += row[i] * w_rel[i];
  for (int off = 32; off > 0; off >>= 1) s += __shfl_down(s, off, 64);
  if (lane == 0) rel_w[tr] = 1.f / (1.f + __expf(-(s + b_rel[0])));
}

__global__ void cvt_f32_bf16(const float* __restrict__ in, u16* __restrict__ out, int n4) {
  int i = blockIdx.x * blockDim.x + threadIdx.x;
  if (i >= n4) return;
  float4 v = ((const float4*)in)[i];
  ushort4 o;
  o.x = f2bf(v.x); o.y = f2bf(v.y); o.z = f2bf(v.z); o.w = f2bf(v.w);
  ((ushort4*)out)[i] = o;
}

// all four 1024x1024 weight matrices in one launch: 4*262144 float4's
__global__ void cvt_w4(const float* __restrict__ Wq, const float* __restrict__ Wk,
                       const float* __restrict__ Wv, const float* __restrict__ Wo,
                       u16* __restrict__ Wcat, u16* __restrict__ Wob) {
  const int i = blockIdx.x * 256 + threadIdx.x;     // 0 .. 1048575
  const int w = i >> 18;                            // 262144 float4 per matrix
  const int j = i & 0x3ffff;
  const float* src = (w == 0) ? Wq : (w == 1) ? Wk : (w == 2) ? Wv : Wo;
  u16* dst = (w == 3) ? Wob : (Wcat + ((size_t)w << 20));
  float4 v = ((const float4*)src)[j];
  ushort4 o;
  o.x = f2bf(v.x); o.y = f2bf(v.y); o.z = f2bf(v.z); o.w = f2bf(v.w);
  ((ushort4*)dst)[j] = o;
}

// ---------------------------------------------------------------- GEMM mainloop
// A [M,K] row-major bf16, B [N,K] row-major bf16 (out = x@W.T)
// 128x128 tile, BK=32, 4 waves, each wave 64x64 = 4x4 mfma_16x16x32 tiles.

__device__ __forceinline__ void gemm_mainloop(const u16* __restrict__ A,
                                              const u16* __restrict__ B,
                                              u16* As, u16* Bs,
                                              int m0, int n0, int K,
                                              f32x4 (&acc)[4][4]) {
  const int tid  = threadIdx.x;
  const int wave = tid >> 6;
  const int lane = tid & 63;

  const int srow = wave * 32 + (lane >> 2);
  const int scol = (lane & 3) * 8;
  const u16* pa0 = A + (size_t)(m0 + srow) * K + scol;
  const u16* pa1 = pa0 + (size_t)16 * K;
  const u16* pb0 = B + (size_t)(n0 + srow) * K + scol;
  const u16* pb1 = pb0 + (size_t)16 * K;
  u16* la0 = As + wave * 1024;   // wave-uniform LDS bases (elements)
  u16* la1 = la0 + 512;
  u16* lb0 = Bs + wave * 1024;
  u16* lb1 = lb0 + 512;

  const int fr = lane & 15;      // m (A) / n (B) within 16
  const int fq = lane >> 4;      // k-chunk quad
  const int mb = (wave >> 1) * 64;
  const int nb = (wave & 1) * 64;

  for (int k0 = 0; k0 < K; k0 += 32) {
    gld_lds16(pa0, la0); gld_lds16(pa1, la1);
    gld_lds16(pb0, lb0); gld_lds16(pb1, lb1);
    pa0 += 32; pa1 += 32; pb0 += 32; pb1 += 32;
    __syncthreads();               // drains vmcnt (incl. global_load_lds)
    short8 af[4], bg[4];
#pragma unroll
    for (int i = 0; i < 4; ++i) {
      af[i] = *(const short8*)(As + (mb + i * 16 + fr) * 32 + fq * 8);
      bg[i] = *(const short8*)(Bs + (nb + i * 16 + fr) * 32 + fq * 8);
    }
#pragma unroll
    for (int i = 0; i < 4; ++i)
#pragma unroll
      for (int j = 0; j < 4; ++j)
        acc[i][j] = __builtin_amdgcn_mfma_f32_16x16x32_bf16(af[i], bg[j], acc[i][j], 0, 0, 0);
    __syncthreads();
  }
}

// GEMM1: X[16384,1024] @ Wcat[3072,1024].T -> Q/K/V stored TRANSPOSED [t][d][b]
__global__ __launch_bounds__(256)
void gemm_qkv(const u16* __restrict__ A, const u16* __restrict__ B,
              const float* __restrict__ bq,
              u16* __restrict__ Qt, u16* __restrict__ Kt, u16* __restrict__ Vt) {
  __shared__ __align__(16) u16 smem[128 * 136];   // 34KB; mainloop uses first 16KB
  u16* As = smem;
  u16* Bs = smem + 4096;
  const int m0 = blockIdx.y * 128;
  const int n0 = blockIdx.x * 128;
  f32x4 acc[4][4];
#pragma unroll
  for (int i = 0; i < 4; ++i)
#pragma unroll
    for (int j = 0; j < 4; ++j) acc[i][j] = (f32x4){0.f, 0.f, 0.f, 0.f};

  gemm_mainloop(A, B, As, Bs, m0, n0, 1024, acc);
  // mainloop's trailing __syncthreads guarantees all LDS reads are done

  const int lane = threadIdx.x & 63;
  const int wave = threadIdx.x >> 6;
  const int mb = (wave >> 1) * 64, nb = (wave & 1) * 64;
  const int colw = lane & 15, roww = (lane >> 4) * 4;
  const int sel = n0 >> 10;                    // uniform: which of Q/K/V

  // scatter acc into smem as [d_local][b_local] (pad 136 keeps 16B row align)
#pragma unroll
  for (int i = 0; i < 4; ++i) {
#pragma unroll
    for (int j = 0; j < 4; ++j) {
      const int dl = nb + j * 16 + colw;
      const float badd = (sel == 0) ? bq[n0 + dl] : 0.f;
#pragma unroll
      for (int r = 0; r < 4; ++r) {
        const int bl = mb + i * 16 + roww + r;
        smem[dl * 136 + bl] = f2bf(acc[i][j][r] + badd);
      }
    }
  }
  __syncthreads();
  {
    const int row  = threadIdx.x >> 1;         // d_local 0..127
    const int half = threadIdx.x & 1;          // 64 b's each
    const int t = m0 >> 10, b0 = m0 & 1023;
    u16* basep = (sel == 0) ? Qt : (sel == 1) ? Kt : Vt;
    u16* dp = basep + ((size_t)t << 20) + (size_t)((n0 - (sel << 10)) + row) * 1024
            + b0 + half * 64;
    const u16* sp = smem + row * 136 + half * 64;
#pragma unroll
    for (int c = 0; c < 8; ++c)
      ((uint4*)dp)[c] = ((const uint4*)sp)[c];
  }
}

// GEMM2: ctx[16384,1024] @ Wo[1024,1024].T + bo -> fp32 out
__global__ __launch_bounds__(256)
void gemm_out(const u16* __restrict__ A, const u16* __restrict__ B,
              const float* __restrict__ bo, float* __restrict__ out) {
  __shared__ __align__(16) u16 As[4096];
  __shared__ __align__(16) u16 Bs[4096];
  const int m0 = blockIdx.y * 128;
  const int n0 = blockIdx.x * 128;
  f32x4 acc[4][4];
#pragma unroll
  for (int i = 0; i < 4; ++i)
#pragma unroll
    for (int j = 0; j < 4; ++j) acc[i][j] = (f32x4){0.f, 0.f, 0.f, 0.f};

  gemm_mainloop(A, B, As, Bs, m0, n0, 1024, acc);

  const int lane = threadIdx.x & 63;
  const int wave = threadIdx.x >> 6;
  const int mb = (wave >> 1) * 64, nb = (wave & 1) * 64;
  const int colw = lane & 15, roww = (lane >> 4) * 4;
#pragma unroll
  for (int i = 0; i < 4; ++i) {
#pragma unroll
    for (int j = 0; j < 4; ++j) {
      const int gn = n0 + nb + j * 16 + colw;
#pragma unroll
      for (int r = 0; r < 4; ++r) {
        const int gm = m0 + mb + i * 16 + roww + r;
        out[(size_t)gm * 1024 + gn] = acc[i][j][r] + bo[gn];
      }
    }
  }
}

// ---------------------------------------------------------------- attention
// lane = b. Qt/Kt/Vt are [t][d][b] so every load is a wave-wide 128B line.
// Per thread: full softmax over R=8 in registers, fp32 math.
// Output staged via LDS -> coalesced 128B row-segment stores.
__global__ __launch_bounds__(256)
void attn2(const u16* __restrict__ Qt, const u16* __restrict__ Kt,
           const u16* __restrict__ Vt,
           const float* __restrict__ relw, const int* __restrict__ rel_idx,
           const float* __restrict__ bk, const float* __restrict__ bv,
           u16* __restrict__ ctx) {
  const int tid = threadIdx.x;
  const int b = blockIdx.x * 256 + tid;
  const int h = blockIdx.y;
  const int t = blockIdx.z;
  const int hd = h * 64;

  __shared__ __align__(16) u16 ld[256 * 66];   // [b_local][66], pad -> <=2-way banks

  float rw[8]; int ridx[8];
#pragma unroll
  for (int r = 0; r < 8; ++r) { rw[r] = relw[t * 8 + r]; ridx[r] = rel_idx[t * 8 + r]; }

  // q (64 d's, regs) and q.bk
  float q[64]; float qbk = 0.f;
  {
    const u16* qp = Qt + ((size_t)t << 20) + (size_t)hd * 1024 + b;
#pragma unroll
    for (int d = 0; d < 64; ++d) {
      q[d] = bf2f(qp[(size_t)d * 1024]);
      qbk += q[d] * bk[hd + d];
    }
  }
  // scores: s = (rw*(q.Ka) + q.bk)/sqrt(DH)
  float s[8];
#pragma unroll
  for (int r = 0; r < 8; ++r) {
    const u16* kp = Kt + ((size_t)ridx[r] << 20) + (size_t)hd * 1024 + b;
    float a = 0.f;
#pragma unroll
    for (int d = 0; d < 64; ++d) a += q[d] * bf2f(kp[(size_t)d * 1024]);
    s[r] = (rw[r] * a + qbk) * 0.125f;
  }
  // softmax -> w[r] = attn_r * rw_r
  float mx = s[0];
#pragma unroll
  for (int r = 1; r < 8; ++r) mx = fmaxf(mx, s[r]);
  float sum = 0.f; float w[8];
#pragma unroll
  for (int r = 0; r < 8; ++r) { w[r] = __expf(s[r] - mx); sum += w[r]; }
  const float inv = 1.f / sum;
#pragma unroll
  for (int r = 0; r < 8; ++r) w[r] *= inv * rw[r];
  // ctx (softmax sums to 1 -> bv passes straight through)
  float o[64];
#pragma unroll
  for (int d = 0; d < 64; ++d) o[d] = bv[hd + d];
#pragma unroll
  for (int r = 0; r < 8; ++r) {
    const u16* vp = Vt + ((size_t)ridx[r] << 20) + (size_t)hd * 1024 + b;
    const float wr = w[r];
#pragma unroll
    for (int d = 0; d < 64; ++d) o[d] += wr * bf2f(vp[(size_t)d * 1024]);
  }
  // stage [b_local][d] in LDS, then write coalesced 128B segments
#pragma unroll
  for (int c = 0; c < 16; ++c) {
    ushort4 v;
    v.x = f2bf(o[c * 4 + 0]); v.y = f2bf(o[c * 4 + 1]);
    v.z = f2bf(o[c * 4 + 2]); v.w = f2bf(o[c * 4 + 3]);
    *(ushort4*)(ld + tid * 66 + c * 4) = v;
  }
  __syncthreads();
  {
    const int sub = tid & 7;                   // 8 lanes x 16B = one 128B segment
    const int b0 = blockIdx.x * 256;
#pragma unroll
    for (int p = 0; p < 8; ++p) {
      const int bl = p * 32 + (tid >> 3);
      u16* dp = ctx + ((size_t)(t * 1024 + b0 + bl)) * 1024 + hd + sub * 8;
      *(uint4*)dp = *(const uint4*)(ld + bl * 66 + sub * 8);
    }
  }
}

// ---------------------------------------------------------------- launch

extern "C" void kernel_launch(void* const* d_in, const int* in_sizes, int n_in,
                              void* d_out, int out_size, void* d_ws, size_t ws_size,
                              hipStream_t stream) {
  const float* table = (const float*)d_in[0];
  const float* rele  = (const float*)d_in[1];
  const int*   ridx  = (const int*)d_in[2];
  const float* Wq    = (const float*)d_in[3];
  const float* bq    = (const float*)d_in[4];
  const float* Wk    = (const float*)d_in[5];
  const float* bk    = (const float*)d_in[6];
  const float* Wv    = (const float*)d_in[7];
  const float* bv    = (const float*)d_in[8];
  const float* Wo    = (const float*)d_in[9];
  const float* bo    = (const float*)d_in[10];
  const float* wr    = (const float*)d_in[11];
  const float* br    = (const float*)d_in[12];
  float* out = (float*)d_out;

  char* ws = (char*)d_ws;
  const size_t MB = 1024 * 1024;
  u16*  Xbf  = (u16*)(ws);                    // 32 MB  [16384,1024] bf16 (also ctx)
  u16*  Kt   = (u16*)(ws + 32  * MB);         // 32 MB  [16][1024 d][1024 b]
  u16*  Vt   = (u16*)(ws + 64  * MB);         // 32 MB
  u16*  Qt   = (u16*)(ws + 96  * MB);         // 32 MB
  u16*  Wcat = (u16*)(ws + 128 * MB);         // 6 MB   [3072,1024] (Wq|Wk|Wv)
  u16*  Wob  = (u16*)(ws + 134 * MB);         // 2 MB
  float* relw = (float*)(ws + 136 * MB);      // 512 B
  u16*  ctxb = Xbf;                           // reuse: Xbf dead after gemm_qkv

  relw_kernel<<<128, 64, 0, stream>>>(rele, wr, br, relw);
  cvt_f32_bf16<<<16384, 256, 0, stream>>>(table, Xbf, 4194304);
  cvt_w4<<<4096, 256, 0, stream>>>(Wq, Wk, Wv, Wo, Wcat, Wob);

  gemm_qkv<<<dim3(24, 128), 256, 0, stream>>>(Xbf, Wcat, bq, Qt, Kt, Vt);
  attn2<<<dim3(4, 16, 16), 256, 0, stream>>>(Qt, Kt, Vt, relw, ridx, bk, bv, ctxb);
  gemm_out<<<dim3(8, 128), 256, 0, stream>>>(ctxb, Wob, bo, out);
}

// Round 4
// 472.427 us; speedup vs baseline: 1.0404x; 1.0404x over previous
//
#include <hip/hip_runtime.h>

// CrossTableAttention on MI355X (gfx950)
// T=16 B=1024 D=1024 R=8 H=16 DH=64
//
// R3: replace attn2 (latency-bound: 2B scalar loads, q[64]/o[64] reg arrays)
//     with attn4: streaming over d, 2 b's per thread, all loads 4B coalesced,
//     acc[8][2] only, output staged via LDS in two 32-d halves.
//     gemm_qkv / gemm_out / converts unchanged from R2 (measured good).

typedef unsigned short u16;
typedef __attribute__((ext_vector_type(8))) short short8;   // 8 bf16 = 4 VGPRs
typedef __attribute__((ext_vector_type(4))) float f32x4;

__device__ __forceinline__ float bf2f(u16 u) {
  unsigned int x = ((unsigned int)u) << 16;
  return __uint_as_float(x);
}
__device__ __forceinline__ float bflo(unsigned int u) {   // low bf16 of a packed pair
  return __uint_as_float(u << 16);
}
__device__ __forceinline__ float bfhi(unsigned int u) {   // high bf16
  return __uint_as_float(u & 0xffff0000u);
}
__device__ __forceinline__ u16 f2bf(float f) {
  unsigned int x = __float_as_uint(f);
  unsigned int r = (x + 0x7fffu + ((x >> 16) & 1u)) >> 16;   // RNE
  return (u16)r;
}

// async global->LDS, 16B per lane; lds dest is wave-uniform base + lane*16
__device__ __forceinline__ void gld_lds16(const void* g, void* l) {
  __builtin_amdgcn_global_load_lds(
      (const __attribute__((address_space(1))) unsigned int*)(unsigned long long)g,
      (__attribute__((address_space(3))) unsigned int*)(unsigned int)(unsigned long long)l,
      16, 0, 0);
}

// ---------------------------------------------------------------- prep kernels

__global__ void relw_kernel(const float* __restrict__ rel_embs,
                            const float* __restrict__ w_rel,
                            const float* __restrict__ b_rel,
                            float* __restrict__ rel_w) {
  const int tr = blockIdx.x;            // t*8 + r, 128 total
  const float* row = rel_embs + (size_t)tr * 1024;
  const int lane = threadIdx.x;         // 64 threads
  float s = 0.f;
  for (int i = lane; i < 1024; i += 64) s += row[i] * w_rel[i];
  for (int off = 32; off > 0; off >>= 1) s += __shfl_down(s, off, 64);
  if (lane == 0) rel_w[tr] = 1.f / (1.f + __expf(-(s + b_rel[0])));
}

__global__ void cvt_f32_bf16(const float* __restrict__ in, u16* __restrict__ out, int n4) {
  int i = blockIdx.x * blockDim.x + threadIdx.x;
  if (i >= n4) return;
  float4 v = ((const float4*)in)[i];
  ushort4 o;
  o.x = f2bf(v.x); o.y = f2bf(v.y); o.z = f2bf(v.z); o.w = f2bf(v.w);
  ((ushort4*)out)[i] = o;
}

// all four 1024x1024 weight matrices in one launch: 4*262144 float4's
__global__ void cvt_w4(const float* __restrict__ Wq, const float* __restrict__ Wk,
                       const float* __restrict__ Wv, const float* __restrict__ Wo,
                       u16* __restrict__ Wcat, u16* __restrict__ Wob) {
  const int i = blockIdx.x * 256 + threadIdx.x;     // 0 .. 1048575
  const int w = i >> 18;                            // 262144 float4 per matrix
  const int j = i & 0x3ffff;
  const float* src = (w == 0) ? Wq : (w == 1) ? Wk : (w == 2) ? Wv : Wo;
  u16* dst = (w == 3) ? Wob : (Wcat + ((size_t)w << 20));
  float4 v = ((const float4*)src)[j];
  ushort4 o;
  o.x = f2bf(v.x); o.y = f2bf(v.y); o.z = f2bf(v.z); o.w = f2bf(v.w);
  ((ushort4*)dst)[j] = o;
}

// ---------------------------------------------------------------- GEMM mainloop
// A [M,K] row-major bf16, B [N,K] row-major bf16 (out = x@W.T)
// 128x128 tile, BK=32, 4 waves, each wave 64x64 = 4x4 mfma_16x16x32 tiles.

__device__ __forceinline__ void gemm_mainloop(const u16* __restrict__ A,
                                              const u16* __restrict__ B,
                                              u16* As, u16* Bs,
                                              int m0, int n0, int K,
                                              f32x4 (&acc)[4][4]) {
  const int tid  = threadIdx.x;
  const int wave = tid >> 6;
  const int lane = tid & 63;

  const int srow = wave * 32 + (lane >> 2);
  const int scol = (lane & 3) * 8;
  const u16* pa0 = A + (size_t)(m0 + srow) * K + scol;
  const u16* pa1 = pa0 + (size_t)16 * K;
  const u16* pb0 = B + (size_t)(n0 + srow) * K + scol;
  const u16* pb1 = pb0 + (size_t)16 * K;
  u16* la0 = As + wave * 1024;   // wave-uniform LDS bases (elements)
  u16* la1 = la0 + 512;
  u16* lb0 = Bs + wave * 1024;
  u16* lb1 = lb0 + 512;

  const int fr = lane & 15;      // m (A) / n (B) within 16
  const int fq = lane >> 4;      // k-chunk quad
  const int mb = (wave >> 1) * 64;
  const int nb = (wave & 1) * 64;

  for (int k0 = 0; k0 < K; k0 += 32) {
    gld_lds16(pa0, la0); gld_lds16(pa1, la1);
    gld_lds16(pb0, lb0); gld_lds16(pb1, lb1);
    pa0 += 32; pa1 += 32; pb0 += 32; pb1 += 32;
    __syncthreads();               // drains vmcnt (incl. global_load_lds)
    short8 af[4], bg[4];
#pragma unroll
    for (int i = 0; i < 4; ++i) {
      af[i] = *(const short8*)(As + (mb + i * 16 + fr) * 32 + fq * 8);
      bg[i] = *(const short8*)(Bs + (nb + i * 16 + fr) * 32 + fq * 8);
    }
#pragma unroll
    for (int i = 0; i < 4; ++i)
#pragma unroll
      for (int j = 0; j < 4; ++j)
        acc[i][j] = __builtin_amdgcn_mfma_f32_16x16x32_bf16(af[i], bg[j], acc[i][j], 0, 0, 0);
    __syncthreads();
  }
}

// GEMM1: X[16384,1024] @ Wcat[3072,1024].T -> Q/K/V stored TRANSPOSED [t][d][b]
__global__ __launch_bounds__(256)
void gemm_qkv(const u16* __restrict__ A, const u16* __restrict__ B,
              const float* __restrict__ bq,
              u16* __restrict__ Qt, u16* __restrict__ Kt, u16* __restrict__ Vt) {
  __shared__ __align__(16) u16 smem[128 * 136];   // 34KB; mainloop uses first 16KB
  u16* As = smem;
  u16* Bs = smem + 4096;
  const int m0 = blockIdx.y * 128;
  const int n0 = blockIdx.x * 128;
  f32x4 acc[4][4];
#pragma unroll
  for (int i = 0; i < 4; ++i)
#pragma unroll
    for (int j = 0; j < 4; ++j) acc[i][j] = (f32x4){0.f, 0.f, 0.f, 0.f};

  gemm_mainloop(A, B, As, Bs, m0, n0, 1024, acc);
  // mainloop's trailing __syncthreads guarantees all LDS reads are done

  const int lane = threadIdx.x & 63;
  const int wave = threadIdx.x >> 6;
  const int mb = (wave >> 1) * 64, nb = (wave & 1) * 64;
  const int colw = lane & 15, roww = (lane >> 4) * 4;
  const int sel = n0 >> 10;                    // uniform: which of Q/K/V

  // scatter acc into smem as [d_local][b_local] (pad 136 keeps 16B row align)
#pragma unroll
  for (int i = 0; i < 4; ++i) {
#pragma unroll
    for (int j = 0; j < 4; ++j) {
      const int dl = nb + j * 16 + colw;
      const float badd = (sel == 0) ? bq[n0 + dl] : 0.f;
#pragma unroll
      for (int r = 0; r < 4; ++r) {
        const int bl = mb + i * 16 + roww + r;
        smem[dl * 136 + bl] = f2bf(acc[i][j][r] + badd);
      }
    }
  }
  __syncthreads();
  {
    const int row  = threadIdx.x >> 1;         // d_local 0..127
    const int half = threadIdx.x & 1;          // 64 b's each
    const int t = m0 >> 10, b0 = m0 & 1023;
    u16* basep = (sel == 0) ? Qt : (sel == 1) ? Kt : Vt;
    u16* dp = basep + ((size_t)t << 20) + (size_t)((n0 - (sel << 10)) + row) * 1024
            + b0 + half * 64;
    const u16* sp = smem + row * 136 + half * 64;
#pragma unroll
    for (int c = 0; c < 8; ++c)
      ((uint4*)dp)[c] = ((const uint4*)sp)[c];
  }
}

// GEMM2: ctx[16384,1024] @ Wo[1024,1024].T + bo -> fp32 out
__global__ __launch_bounds__(256)
void gemm_out(const u16* __restrict__ A, const u16* __restrict__ B,
              const float* __restrict__ bo, float* __restrict__ out) {
  __shared__ __align__(16) u16 As[4096];
  __shared__ __align__(16) u16 Bs[4096];
  const int m0 = blockIdx.y * 128;
  const int n0 = blockIdx.x * 128;
  f32x4 acc[4][4];
#pragma unroll
  for (int i = 0; i < 4; ++i)
#pragma unroll
    for (int j = 0; j < 4; ++j) acc[i][j] = (f32x4){0.f, 0.f, 0.f, 0.f};

  gemm_mainloop(A, B, As, Bs, m0, n0, 1024, acc);

  const int lane = threadIdx.x & 63;
  const int wave = threadIdx.x >> 6;
  const int mb = (wave >> 1) * 64, nb = (wave & 1) * 64;
  const int colw = lane & 15, roww = (lane >> 4) * 4;
#pragma unroll
  for (int i = 0; i < 4; ++i) {
#pragma unroll
    for (int j = 0; j < 4; ++j) {
      const int gn = n0 + nb + j * 16 + colw;
#pragma unroll
      for (int r = 0; r < 4; ++r) {
        const int gm = m0 + mb + i * 16 + roww + r;
        out[(size_t)gm * 1024 + gn] = acc[i][j][r] + bo[gn];
      }
    }
  }
}

// ---------------------------------------------------------------- attention
// attn4: thread owns b-pair (2*tid, 2*tid+1); streams over d. Every global
// load is a packed uint (2 bf16, consecutive lanes contiguous -> 256B/wave).
// score[r] accumulated in regs; output staged per 32-d half via LDS, then
// written as coalesced row segments of row-major ctx.
__global__ __launch_bounds__(256)
void attn4(const u16* __restrict__ Qt, const u16* __restrict__ Kt,
           const u16* __restrict__ Vt,
           const float* __restrict__ relw, const int* __restrict__ rel_idx,
           const float* __restrict__ bk, const float* __restrict__ bv,
           u16* __restrict__ ctx) {
  const int tid = threadIdx.x;
  const int h = blockIdx.y, t = blockIdx.z;
  const int b0 = blockIdx.x * 512;          // block covers b0 .. b0+511
  const int bb = b0 + 2 * tid;              // thread's b pair
  const int hd = h * 64;

  __shared__ u16  st[512 * 36];             // [512 b][32 d + 4 pad]  36.9KB
  __shared__ float bks[64], bvs[64], rws[8];
  __shared__ int   rids[8];

  if (tid < 64) { bks[tid] = bk[hd + tid]; bvs[tid] = bv[hd + tid]; }
  else if (tid < 72) { rws[tid - 64] = relw[t * 8 + (tid - 64)];
                       rids[tid - 64] = rel_idx[t * 8 + (tid - 64)]; }
  __syncthreads();

  // element offsets at d=0 into [t][1024 d][1024 b] arrays
  const unsigned qoff = ((unsigned)t << 20) + ((unsigned)hd << 10) + (unsigned)bb;
  unsigned koff[8];
#pragma unroll
  for (int r = 0; r < 8; ++r)
    koff[r] = ((unsigned)rids[r] << 20) + ((unsigned)hd << 10) + (unsigned)bb;

  // ---- scores: stream d, acc[r][e] = sum_d q_e[d]*k_r_e[d]
  float acc[8][2];
#pragma unroll
  for (int r = 0; r < 8; ++r) { acc[r][0] = 0.f; acc[r][1] = 0.f; }
  float qbk0 = 0.f, qbk1 = 0.f;
#pragma unroll 4
  for (int d = 0; d < 64; ++d) {
    const unsigned qw = *(const unsigned*)(Qt + qoff + d * 1024);
    const float q0 = bflo(qw), q1 = bfhi(qw);
    const float bkd = bks[d];
    qbk0 += q0 * bkd; qbk1 += q1 * bkd;
#pragma unroll
    for (int r = 0; r < 8; ++r) {
      const unsigned kw = *(const unsigned*)(Kt + koff[r] + d * 1024);
      acc[r][0] += q0 * bflo(kw);
      acc[r][1] += q1 * bfhi(kw);
    }
  }

  // ---- softmax -> w[r][e] = attn * rw
  float w[8][2];
#pragma unroll
  for (int e = 0; e < 2; ++e) {
    const float qbk = e ? qbk1 : qbk0;
    float s[8], mx = -1e30f;
#pragma unroll
    for (int r = 0; r < 8; ++r) {
      s[r] = (rws[r] * acc[r][e] + qbk) * 0.125f;
      mx = fmaxf(mx, s[r]);
    }
    float sum = 0.f;
#pragma unroll
    for (int r = 0; r < 8; ++r) { s[r] = __expf(s[r] - mx); sum += s[r]; }
    const float inv = 1.f / sum;
#pragma unroll
    for (int r = 0; r < 8; ++r) w[r][e] = s[r] * inv * rws[r];
  }

  // ---- context: two 32-d halves; stage [b][d] in LDS, coalesced writeout
  for (int half = 0; half < 2; ++half) {
#pragma unroll
    for (int dp = 0; dp < 32; dp += 2) {
      const int d = half * 32 + dp;
      float o00 = bvs[d],     o01 = bvs[d];      // d,   b / b+1
      float o10 = bvs[d + 1], o11 = bvs[d + 1];  // d+1, b / b+1
#pragma unroll
      for (int r = 0; r < 8; ++r) {
        const unsigned vw0 = *(const unsigned*)(Vt + koff[r] + d * 1024);
        const unsigned vw1 = *(const unsigned*)(Vt + koff[r] + (d + 1) * 1024);
        o00 += w[r][0] * bflo(vw0); o01 += w[r][1] * bfhi(vw0);
        o10 += w[r][0] * bflo(vw1); o11 += w[r][1] * bfhi(vw1);
      }
      const unsigned p0 = (unsigned)f2bf(o00) | ((unsigned)f2bf(o10) << 16);
      const unsigned p1 = (unsigned)f2bf(o01) | ((unsigned)f2bf(o11) << 16);
      *(unsigned*)(st + (2 * tid)     * 36 + dp) = p0;   // 4B-aligned (even idx)
      *(unsigned*)(st + (2 * tid + 1) * 36 + dp) = p1;
    }
    __syncthreads();
    // writeout: 512 rows x 64B (32 d); 8 lanes x 8B per row, 16 passes
    {
      const int sub = tid & 7;
      const int rbase = tid >> 3;                // 0..31
#pragma unroll
      for (int p = 0; p < 16; ++p) {
        const int row = p * 32 + rbase;
        const uint2 v = *(const uint2*)(st + row * 36 + sub * 4);
        *(uint2*)(ctx + ((size_t)(t * 1024 + b0 + row)) * 1024
                  + hd + half * 32 + sub * 4) = v;
      }
    }
    __syncthreads();   // st reused by next half
  }
}

// ---------------------------------------------------------------- launch

extern "C" void kernel_launch(void* const* d_in, const int* in_sizes, int n_in,
                              void* d_out, int out_size, void* d_ws, size_t ws_size,
                              hipStream_t stream) {
  const float* table = (const float*)d_in[0];
  const float* rele  = (const float*)d_in[1];
  const int*   ridx  = (const int*)d_in[2];
  const float* Wq    = (const float*)d_in[3];
  const float* bq    = (const float*)d_in[4];
  const float* Wk    = (const float*)d_in[5];
  const float* bk    = (const float*)d_in[6];
  const float* Wv    = (const float*)d_in[7];
  const float* bv    = (const float*)d_in[8];
  const float* Wo    = (const float*)d_in[9];
  const float* bo    = (const float*)d_in[10];
  const float* wr    = (const float*)d_in[11];
  const float* br    = (const float*)d_in[12];
  float* out = (float*)d_out;

  char* ws = (char*)d_ws;
  const size_t MB = 1024 * 1024;
  u16*  Xbf  = (u16*)(ws);                    // 32 MB  [16384,1024] bf16 (also ctx)
  u16*  Kt   = (u16*)(ws + 32  * MB);         // 32 MB  [16][1024 d][1024 b]
  u16*  Vt   = (u16*)(ws + 64  * MB);         // 32 MB
  u16*  Qt   = (u16*)(ws + 96  * MB);         // 32 MB
  u16*  Wcat = (u16*)(ws + 128 * MB);         // 6 MB   [3072,1024] (Wq|Wk|Wv)
  u16*  Wob  = (u16*)(ws + 134 * MB);         // 2 MB
  float* relw = (float*)(ws + 136 * MB);      // 512 B
  u16*  ctxb = Xbf;                           // reuse: Xbf dead after gemm_qkv

  relw_kernel<<<128, 64, 0, stream>>>(rele, wr, br, relw);
  cvt_f32_bf16<<<16384, 256, 0, stream>>>(table, Xbf, 4194304);
  cvt_w4<<<4096, 256, 0, stream>>>(Wq, Wk, Wv, Wo, Wcat, Wob);

  gemm_qkv<<<dim3(24, 128), 256, 0, stream>>>(Xbf, Wcat, bq, Qt, Kt, Vt);
  attn4<<<dim3(2, 16, 16), 256, 0, stream>>>(Qt, Kt, Vt, relw, ridx, bk, bv, ctxb);
  gemm_out<<<dim3(8, 128), 256, 0, stream>>>(ctxb, Wob, bo, out);
}

// Round 5
// 424.944 us; speedup vs baseline: 1.1567x; 1.1117x over previous
//
#include <hip/hip_runtime.h>

// CrossTableAttention on MI355X (gfx950)
// T=16 B=1024 D=1024 R=8 H=16 DH=64
//
// R4: (1) LDS chunk XOR-swizzle in gemm_mainloop (slot = chunk ^ ((row>>1)&3))
//         -> ds_read_b128 2 lanes/bank-group instead of 8 (R2's "neutral"
//         claim was bad arithmetic: there are 8 four-bank groups, not 4).
//     (2) attn5: 1 b per thread (4096 waves = 16 waves/CU, 2x latency hiding)
//         -> discriminates latency-bound vs LLC-BW-bound attention.

typedef unsigned short u16;
typedef __attribute__((ext_vector_type(8))) short short8;   // 8 bf16 = 4 VGPRs
typedef __attribute__((ext_vector_type(4))) float f32x4;

__device__ __forceinline__ float bf2f(u16 u) {
  unsigned int x = ((unsigned int)u) << 16;
  return __uint_as_float(x);
}
__device__ __forceinline__ u16 f2bf(float f) {
  unsigned int x = __float_as_uint(f);
  unsigned int r = (x + 0x7fffu + ((x >> 16) & 1u)) >> 16;   // RNE
  return (u16)r;
}

// async global->LDS, 16B per lane; lds dest is wave-uniform base + lane*16
__device__ __forceinline__ void gld_lds16(const void* g, void* l) {
  __builtin_amdgcn_global_load_lds(
      (const __attribute__((address_space(1))) unsigned int*)(unsigned long long)g,
      (__attribute__((address_space(3))) unsigned int*)(unsigned int)(unsigned long long)l,
      16, 0, 0);
}

// ---------------------------------------------------------------- prep kernels

__global__ void relw_kernel(const float* __restrict__ rel_embs,
                            const float* __restrict__ w_rel,
                            const float* __restrict__ b_rel,
                            float* __restrict__ rel_w) {
  const int tr = blockIdx.x;            // t*8 + r, 128 total
  const float* row = rel_embs + (size_t)tr * 1024;
  const int lane = threadIdx.x;         // 64 threads
  float s = 0.f;
  for (int i = lane; i < 1024; i += 64) s += row[i] * w_rel[i];
  for (int off = 32; off > 0; off >>= 1) s += __shfl_down(s, off, 64);
  if (lane == 0) rel_w[tr] = 1.f / (1.f + __expf(-(s + b_rel[0])));
}

__global__ void cvt_f32_bf16(const float* __restrict__ in, u16* __restrict__ out, int n4) {
  int i = blockIdx.x * blockDim.x + threadIdx.x;
  if (i >= n4) return;
  float4 v = ((const float4*)in)[i];
  ushort4 o;
  o.x = f2bf(v.x); o.y = f2bf(v.y); o.z = f2bf(v.z); o.w = f2bf(v.w);
  ((ushort4*)out)[i] = o;
}

// all four 1024x1024 weight matrices in one launch: 4*262144 float4's
__global__ void cvt_w4(const float* __restrict__ Wq, const float* __restrict__ Wk,
                       const float* __restrict__ Wv, const float* __restrict__ Wo,
                       u16* __restrict__ Wcat, u16* __restrict__ Wob) {
  const int i = blockIdx.x * 256 + threadIdx.x;     // 0 .. 1048575
  const int w = i >> 18;                            // 262144 float4 per matrix
  const int j = i & 0x3ffff;
  const float* src = (w == 0) ? Wq : (w == 1) ? Wk : (w == 2) ? Wv : Wo;
  u16* dst = (w == 3) ? Wob : (Wcat + ((size_t)w << 20));
  float4 v = ((const float4*)src)[j];
  ushort4 o;
  o.x = f2bf(v.x); o.y = f2bf(v.y); o.z = f2bf(v.z); o.w = f2bf(v.w);
  ((ushort4*)dst)[j] = o;
}

// ---------------------------------------------------------------- GEMM mainloop
// A [M,K] row-major bf16, B [N,K] row-major bf16 (out = x@W.T)
// 128x128 tile, BK=32, 4 waves, each wave 64x64 = 4x4 mfma_16x16x32 tiles.
// LDS layout: [block-row][4 chunks of 8 elem]; slot c holds global chunk
// c ^ ((row>>1)&3)  -> fragment ds_read_b128 spreads 2 lanes per 4-bank group.

__device__ __forceinline__ void gemm_mainloop(const u16* __restrict__ A,
                                              const u16* __restrict__ B,
                                              u16* As, u16* Bs,
                                              int m0, int n0, int K,
                                              f32x4 (&acc)[4][4]) {
  const int tid  = threadIdx.x;
  const int wave = tid >> 6;
  const int lane = tid & 63;

  const int srow   = wave * 32 + (lane >> 2);             // block-local row
  const int gchunk = (lane & 3) ^ ((lane >> 3) & 3);      // swizzled source chunk
  const u16* pa0 = A + (size_t)(m0 + srow) * K + gchunk * 8;
  const u16* pa1 = pa0 + (size_t)16 * K;
  const u16* pb0 = B + (size_t)(n0 + srow) * K + gchunk * 8;
  const u16* pb1 = pb0 + (size_t)16 * K;
  u16* la0 = As + wave * 1024;   // wave-uniform LDS bases (elements)
  u16* la1 = la0 + 512;
  u16* lb0 = Bs + wave * 1024;
  u16* lb1 = lb0 + 512;

  const int fr  = lane & 15;     // m (A) / n (B) within 16
  const int fq  = lane >> 4;     // k-chunk quad
  const int swz = (fr >> 1) & 3; // row-dependent slot XOR
  const int mb = (wave >> 1) * 64;
  const int nb = (wave & 1) * 64;

  for (int k0 = 0; k0 < K; k0 += 32) {
    gld_lds16(pa0, la0); gld_lds16(pa1, la1);
    gld_lds16(pb0, lb0); gld_lds16(pb1, lb1);
    pa0 += 32; pa1 += 32; pb0 += 32; pb1 += 32;
    __syncthreads();               // drains vmcnt (incl. global_load_lds)
    short8 af[4], bg[4];
#pragma unroll
    for (int i = 0; i < 4; ++i) {
      af[i] = *(const short8*)(As + (mb + i * 16 + fr) * 32 + (fq ^ swz) * 8);
      bg[i] = *(const short8*)(Bs + (nb + i * 16 + fr) * 32 + (fq ^ swz) * 8);
    }
#pragma unroll
    for (int i = 0; i < 4; ++i)
#pragma unroll
      for (int j = 0; j < 4; ++j)
        acc[i][j] = __builtin_amdgcn_mfma_f32_16x16x32_bf16(af[i], bg[j], acc[i][j], 0, 0, 0);
    __syncthreads();
  }
}

// GEMM1: X[16384,1024] @ Wcat[3072,1024].T -> Q/K/V stored TRANSPOSED [t][d][b]
__global__ __launch_bounds__(256)
void gemm_qkv(const u16* __restrict__ A, const u16* __restrict__ B,
              const float* __restrict__ bq,
              u16* __restrict__ Qt, u16* __restrict__ Kt, u16* __restrict__ Vt) {
  __shared__ __align__(16) u16 smem[128 * 136];   // 34KB; mainloop uses first 16KB
  u16* As = smem;
  u16* Bs = smem + 4096;
  const int m0 = blockIdx.y * 128;
  const int n0 = blockIdx.x * 128;
  f32x4 acc[4][4];
#pragma unroll
  for (int i = 0; i < 4; ++i)
#pragma unroll
    for (int j = 0; j < 4; ++j) acc[i][j] = (f32x4){0.f, 0.f, 0.f, 0.f};

  gemm_mainloop(A, B, As, Bs, m0, n0, 1024, acc);
  // mainloop's trailing __syncthreads guarantees all LDS reads are done

  const int lane = threadIdx.x & 63;
  const int wave = threadIdx.x >> 6;
  const int mb = (wave >> 1) * 64, nb = (wave & 1) * 64;
  const int colw = lane & 15, roww = (lane >> 4) * 4;
  const int sel = n0 >> 10;                    // uniform: which of Q/K/V

  // scatter acc into smem as [d_local][b_local] (pad 136 keeps 16B row align)
#pragma unroll
  for (int i = 0; i < 4; ++i) {
#pragma unroll
    for (int j = 0; j < 4; ++j) {
      const int dl = nb + j * 16 + colw;
      const float badd = (sel == 0) ? bq[n0 + dl] : 0.f;
#pragma unroll
      for (int r = 0; r < 4; ++r) {
        const int bl = mb + i * 16 + roww + r;
        smem[dl * 136 + bl] = f2bf(acc[i][j][r] + badd);
      }
    }
  }
  __syncthreads();
  {
    const int row  = threadIdx.x >> 1;         // d_local 0..127
    const int half = threadIdx.x & 1;          // 64 b's each
    const int t = m0 >> 10, b0 = m0 & 1023;
    u16* basep = (sel == 0) ? Qt : (sel == 1) ? Kt : Vt;
    u16* dp = basep + ((size_t)t << 20) + (size_t)((n0 - (sel << 10)) + row) * 1024
            + b0 + half * 64;
    const u16* sp = smem + row * 136 + half * 64;
#pragma unroll
    for (int c = 0; c < 8; ++c)
      ((uint4*)dp)[c] = ((const uint4*)sp)[c];
  }
}

// GEMM2: ctx[16384,1024] @ Wo[1024,1024].T + bo -> fp32 out
__global__ __launch_bounds__(256)
void gemm_out(const u16* __restrict__ A, const u16* __restrict__ B,
              const float* __restrict__ bo, float* __restrict__ out) {
  __shared__ __align__(16) u16 As[4096];
  __shared__ __align__(16) u16 Bs[4096];
  const int m0 = blockIdx.y * 128;
  const int n0 = blockIdx.x * 128;
  f32x4 acc[4][4];
#pragma unroll
  for (int i = 0; i < 4; ++i)
#pragma unroll
    for (int j = 0; j < 4; ++j) acc[i][j] = (f32x4){0.f, 0.f, 0.f, 0.f};

  gemm_mainloop(A, B, As, Bs, m0, n0, 1024, acc);

  const int lane = threadIdx.x & 63;
  const int wave = threadIdx.x >> 6;
  const int mb = (wave >> 1) * 64, nb = (wave & 1) * 64;
  const int colw = lane & 15, roww = (lane >> 4) * 4;
#pragma unroll
  for (int i = 0; i < 4; ++i) {
#pragma unroll
    for (int j = 0; j < 4; ++j) {
      const int gn = n0 + nb + j * 16 + colw;
#pragma unroll
      for (int r = 0; r < 4; ++r) {
        const int gm = m0 + mb + i * 16 + roww + r;
        out[(size_t)gm * 1024 + gn] = acc[i][j][r] + bo[gn];
      }
    }
  }
}

// ---------------------------------------------------------------- attention
// attn5: ONE b per thread (262144 threads = 4096 waves = 16 waves/CU).
// Streams d; loads are 2B/lane (128B/wave contiguous). acc[8] in regs.
// Output staged per 32-d half via LDS (pad 34 -> 2-way banks), coalesced rows.
__global__ __launch_bounds__(256)
void attn5(const u16* __restrict__ Qt, const u16* __restrict__ Kt,
           const u16* __restrict__ Vt,
           const float* __restrict__ relw, const int* __restrict__ rel_idx,
           const float* __restrict__ bk, const float* __restrict__ bv,
           u16* __restrict__ ctx) {
  const int tid = threadIdx.x;
  const int h = blockIdx.y, t = blockIdx.z;
  const int b0 = blockIdx.x * 256;          // block covers b0 .. b0+255
  const int b = b0 + tid;
  const int hd = h * 64;

  __shared__ u16  st[256 * 34];             // [256 b][32 d + 2 pad]  17.0KB
  __shared__ float bks[64], bvs[64], rws[8];
  __shared__ int   rids[8];

  if (tid < 64) { bks[tid] = bk[hd + tid]; bvs[tid] = bv[hd + tid]; }
  else if (tid < 72) { rws[tid - 64] = relw[t * 8 + (tid - 64)];
                       rids[tid - 64] = rel_idx[t * 8 + (tid - 64)]; }
  __syncthreads();

  // element offsets at d=0 into [t][1024 d][1024 b] arrays
  const unsigned qoff = ((unsigned)t << 20) + ((unsigned)hd << 10) + (unsigned)b;
  unsigned koff[8];
#pragma unroll
  for (int r = 0; r < 8; ++r)
    koff[r] = ((unsigned)rids[r] << 20) + ((unsigned)hd << 10) + (unsigned)b;

  // ---- scores
  float acc[8];
#pragma unroll
  for (int r = 0; r < 8; ++r) acc[r] = 0.f;
  float qbk = 0.f;
#pragma unroll 4
  for (int d = 0; d < 64; ++d) {
    const float q = bf2f(Qt[qoff + d * 1024]);
    qbk += q * bks[d];
#pragma unroll
    for (int r = 0; r < 8; ++r)
      acc[r] += q * bf2f(Kt[koff[r] + d * 1024]);
  }

  // ---- softmax -> w[r] = attn_r * rw_r
  float w[8];
  {
    float s[8], mx = -1e30f;
#pragma unroll
    for (int r = 0; r < 8; ++r) {
      s[r] = (rws[r] * acc[r] + qbk) * 0.125f;
      mx = fmaxf(mx, s[r]);
    }
    float sum = 0.f;
#pragma unroll
    for (int r = 0; r < 8; ++r) { s[r] = __expf(s[r] - mx); sum += s[r]; }
    const float inv = 1.f / sum;
#pragma unroll
    for (int r = 0; r < 8; ++r) w[r] = s[r] * inv * rws[r];
  }

  // ---- context: two 32-d halves; stage [b][d] in LDS, coalesced writeout
  for (int half = 0; half < 2; ++half) {
#pragma unroll
    for (int dp = 0; dp < 32; dp += 2) {
      const int d = half * 32 + dp;
      float o0 = bvs[d];
      float o1 = bvs[d + 1];
#pragma unroll
      for (int r = 0; r < 8; ++r) {
        o0 += w[r] * bf2f(Vt[koff[r] + d * 1024]);
        o1 += w[r] * bf2f(Vt[koff[r] + (d + 1) * 1024]);
      }
      const unsigned p = (unsigned)f2bf(o0) | ((unsigned)f2bf(o1) << 16);
      *(unsigned*)(st + tid * 34 + dp) = p;   // byte 68*tid+2dp, 4B-aligned
    }
    __syncthreads();
    // writeout: 256 rows x 64B (32 d); 8 lanes x 8B per row, 8 passes
    {
      const int sub = tid & 7;
      const int rbase = tid >> 3;              // 0..31
#pragma unroll
      for (int p = 0; p < 8; ++p) {
        const int row = p * 32 + rbase;
        const uint2 v = *(const uint2*)(st + row * 34 + sub * 4);
        *(uint2*)(ctx + ((size_t)(t * 1024 + b0 + row)) * 1024
                  + hd + half * 32 + sub * 4) = v;
      }
    }
    __syncthreads();   // st reused by next half
  }
}

// ---------------------------------------------------------------- launch

extern "C" void kernel_launch(void* const* d_in, const int* in_sizes, int n_in,
                              void* d_out, int out_size, void* d_ws, size_t ws_size,
                              hipStream_t stream) {
  const float* table = (const float*)d_in[0];
  const float* rele  = (const float*)d_in[1];
  const int*   ridx  = (const int*)d_in[2];
  const float* Wq    = (const float*)d_in[3];
  const float* bq    = (const float*)d_in[4];
  const float* Wk    = (const float*)d_in[5];
  const float* bk    = (const float*)d_in[6];
  const float* Wv    = (const float*)d_in[7];
  const float* bv    = (const float*)d_in[8];
  const float* Wo    = (const float*)d_in[9];
  const float* bo    = (const float*)d_in[10];
  const float* wr    = (const float*)d_in[11];
  const float* br    = (const float*)d_in[12];
  float* out = (float*)d_out;

  char* ws = (char*)d_ws;
  const size_t MB = 1024 * 1024;
  u16*  Xbf  = (u16*)(ws);                    // 32 MB  [16384,1024] bf16 (also ctx)
  u16*  Kt   = (u16*)(ws + 32  * MB);         // 32 MB  [16][1024 d][1024 b]
  u16*  Vt   = (u16*)(ws + 64  * MB);         // 32 MB
  u16*  Qt   = (u16*)(ws + 96  * MB);         // 32 MB
  u16*  Wcat = (u16*)(ws + 128 * MB);         // 6 MB   [3072,1024] (Wq|Wk|Wv)
  u16*  Wob  = (u16*)(ws + 134 * MB);         // 2 MB
  float* relw = (float*)(ws + 136 * MB);      // 512 B
  u16*  ctxb = Xbf;                           // reuse: Xbf dead after gemm_qkv

  relw_kernel<<<128, 64, 0, stream>>>(rele, wr, br, relw);
  cvt_f32_bf16<<<16384, 256, 0, stream>>>(table, Xbf, 4194304);
  cvt_w4<<<4096, 256, 0, stream>>>(Wq, Wk, Wv, Wo, Wcat, Wob);

  gemm_qkv<<<dim3(24, 128), 256, 0, stream>>>(Xbf, Wcat, bq, Qt, Kt, Vt);
  attn5<<<dim3(4, 16, 16), 256, 0, stream>>>(Qt, Kt, Vt, relw, ridx, bk, bv, ctxb);
  gemm_out<<<dim3(8, 128), 256, 0, stream>>>(ctxb, Wob, bo, out);
}